// Round 2
// baseline (952.208 us; speedup 1.0000x reference)
//
#include <hip/hip_runtime.h>
#include <math.h>

#define N_USERS 100000
#define N_ITEMS 50000
#define NR      150000
#define N_EDGES 2000000
#define D       64
#define EPS     1e-12f

// ---------------- workspace layout (bytes) ----------------
#define SCAL_OFF 0u                         // float4[NR]      2,400,000
#define CNT_OFF  2400000u                   // int[NR]           600,000
#define OFF_OFF  3000000u                   // int[NR+1]         600,004
#define CUR_OFF  3600016u                   // int[NR]           600,000
#define BSUM_OFF 4200016u                   // int[256]            1,024
#define SLOT_OFF 4201040u                   // int[2*N_EDGES] 16,000,000
#define WS_NEED  (SLOT_OFF + 2u * N_EDGES * 4u)   // ~20.2 MB

// ---------------------------------------------------------------------------
// Per-row scalars: scal[r] = { invn, rsqrt(deg), beta_or_0, 0 }
// One 64-lane wave per row (D == 64).
// ---------------------------------------------------------------------------
__global__ void scal_kernel(const float* __restrict__ x,
                            const float* __restrict__ beta,
                            const float* __restrict__ du,
                            const float* __restrict__ di,
                            float4* __restrict__ scal) {
    int gid  = blockIdx.x * blockDim.x + threadIdx.x;
    int r    = gid >> 6;
    int lane = gid & 63;
    if (r >= NR) return;

    float v  = x[r * D + lane];
    float ss = v * v;
    #pragma unroll
    for (int m = 32; m >= 1; m >>= 1) ss += __shfl_xor(ss, m);

    if (lane == 0) {
        float invn = 1.0f / fmaxf(sqrtf(ss), EPS);
        float deg  = (r < N_USERS) ? du[r] : di[r - N_USERS];
        float b    = (r < N_USERS) ? beta[r] : 0.0f;
        scal[r] = make_float4(invn, rsqrtf(deg), b, 0.0f);
    }
}

// ---------------------------------------------------------------------------
// Degree histogram over the combined 150K-row index space.
// ---------------------------------------------------------------------------
__global__ void count_kernel(const int* __restrict__ u,
                             const int* __restrict__ i,
                             int* __restrict__ cnt) {
    int e = blockIdx.x * blockDim.x + threadIdx.x;
    if (e >= N_EDGES) return;
    atomicAdd(&cnt[u[e]], 1);
    atomicAdd(&cnt[N_USERS + i[e]], 1);
}

// ---------------------------------------------------------------------------
// Scan: per-block exclusive scan (1024) + block sums
// ---------------------------------------------------------------------------
__global__ void scanA_kernel(const int* __restrict__ cnt,
                             int* __restrict__ off,      // per-block exclusive
                             int* __restrict__ bsum,
                             int n) {
    __shared__ int sm[1024];
    int t   = threadIdx.x;
    int idx = blockIdx.x * 1024 + t;
    int v   = (idx < n) ? cnt[idx] : 0;
    sm[t] = v;
    __syncthreads();
    for (int ofs = 1; ofs < 1024; ofs <<= 1) {
        int a = (t >= ofs) ? sm[t - ofs] : 0;
        __syncthreads();
        sm[t] += a;
        __syncthreads();
    }
    if (idx < n) off[idx] = sm[t] - v;          // exclusive within block
    if (t == 1023) bsum[blockIdx.x] = sm[t];    // inclusive total
}

__global__ void scanB_kernel(int* __restrict__ bsum, int nb) {
    __shared__ int sm[256];
    int t = threadIdx.x;
    int v = (t < nb) ? bsum[t] : 0;
    sm[t] = v;
    __syncthreads();
    for (int ofs = 1; ofs < 256; ofs <<= 1) {
        int a = (t >= ofs) ? sm[t - ofs] : 0;
        __syncthreads();
        sm[t] += a;
        __syncthreads();
    }
    if (t < nb) bsum[t] = sm[t] - v;            // exclusive block offsets
}

__global__ void scanC_kernel(int* __restrict__ off,
                             int* __restrict__ cur,
                             const int* __restrict__ bsum,
                             int n) {
    int idx = blockIdx.x * blockDim.x + threadIdx.x;
    if (idx < n) {
        int v = off[idx] + bsum[idx >> 10];
        off[idx] = v;
        cur[idx] = v;
    }
    if (idx == 0) off[n] = 2 * N_EDGES;
}

// ---------------------------------------------------------------------------
// Fill combined adjacency: row u gets item-row index, row (NU+i) gets u.
// ---------------------------------------------------------------------------
__global__ void fill_kernel(const int* __restrict__ u,
                            const int* __restrict__ i,
                            int* __restrict__ cur,
                            int* __restrict__ slots) {
    int e = blockIdx.x * blockDim.x + threadIdx.x;
    if (e >= N_EDGES) return;
    int uu = u[e];
    int ii = N_USERS + i[e];
    slots[atomicAdd(&cur[uu], 1)] = ii;
    slots[atomicAdd(&cur[ii], 1)] = uu;
}

// ---------------------------------------------------------------------------
// Gather: one wave per output row; recompute dot/weight per edge; coalesced
// streaming write of the result row. No fp32 atomics anywhere.
// ---------------------------------------------------------------------------
__global__ void gather_kernel(const float* __restrict__ x,
                              const float4* __restrict__ scal,
                              const int* __restrict__ off,
                              const int* __restrict__ slots,
                              float* __restrict__ out) {
    int gid  = blockIdx.x * blockDim.x + threadIdx.x;
    int r    = gid >> 6;
    int lane = gid & 63;
    if (r >= NR) return;

    float4 sc  = scal[r];
    float  xs  = x[r * D + lane];
    int    s0  = off[r];
    int    s1  = off[r + 1];
    bool   isu = (r < N_USERS);
    float  acc = 0.0f;

    // 1-deep software pipeline: loads for iter s issued at iter s-1
    int    o  = 0;
    float4 so = make_float4(0.f, 0.f, 0.f, 0.f);
    float  xo = 0.0f;
    if (s0 < s1) {
        o  = slots[s0];
        so = scal[o];
        xo = x[o * D + lane];
    }

    for (int s = s0; s < s1; ++s) {
        int    o_c  = o;
        float4 so_c = so;
        float  xo_c = xo;
        if (s + 1 < s1) {                  // prefetch next edge
            o  = slots[s + 1];
            so = scal[o];
            xo = x[o * D + lane];
        }
        (void)o_c;

        float p = xs * xo_c;
        #pragma unroll
        for (int m = 32; m >= 1; m >>= 1) p += __shfl_xor(p, m);

        float b   = isu ? sc.z : so_c.z;
        float sv  = p * sc.x * so_c.x - b;
        float sig = 1.0f / (1.0f + __expf(-sv));
        float w   = 4.0f * sig * (1.0f - sig) * sc.y * so_c.y;
        acc = fmaf(w, xo_c, acc);
    }

    out[r * D + lane] = acc;
}

// ---------------------------------------------------------------------------
// Fallback (round-1 proven path) if workspace is too small
// ---------------------------------------------------------------------------
__global__ void norm_kernel(const float* __restrict__ x,
                            float* __restrict__ invn,
                            int nrows) {
    int gid  = blockIdx.x * blockDim.x + threadIdx.x;
    int wave = gid >> 6;
    int lane = gid & 63;
    if (wave >= nrows) return;
    float v  = x[wave * D + lane];
    float ss = v * v;
    #pragma unroll
    for (int m = 32; m >= 1; m >>= 1) ss += __shfl_xor(ss, m);
    if (lane == 0) invn[wave] = 1.0f / fmaxf(sqrtf(ss), EPS);
}

__global__ void edge_kernel(const float* __restrict__ x,
                            const float* __restrict__ beta,
                            const float* __restrict__ du,
                            const float* __restrict__ di,
                            const int*   __restrict__ u,
                            const int*   __restrict__ i,
                            const float* __restrict__ invn,
                            float* __restrict__ out) {
    int gid  = blockIdx.x * blockDim.x + threadIdx.x;
    int wave = gid >> 6;
    int lane = gid & 63;
    if (wave >= N_EDGES) return;
    int uu = u[wave];
    int ii = i[wave];
    const float xu = x[uu * D + lane];
    const float xi = x[(N_USERS + ii) * D + lane];
    float p = xu * xi;
    #pragma unroll
    for (int m = 32; m >= 1; m >>= 1) p += __shfl_xor(p, m);
    float s   = p * invn[uu] * invn[N_USERS + ii] - beta[uu];
    float sig = 1.0f / (1.0f + __expf(-s));
    float w   = 4.0f * sig * (1.0f - sig) * rsqrtf(du[uu]) * rsqrtf(di[ii]);
    atomicAdd(&out[uu * D + lane],             w * xi);
    atomicAdd(&out[(N_USERS + ii) * D + lane], w * xu);
}

// ---------------------------------------------------------------------------
extern "C" void kernel_launch(void* const* d_in, const int* in_sizes, int n_in,
                              void* d_out, int out_size, void* d_ws, size_t ws_size,
                              hipStream_t stream) {
    const float* x    = (const float*)d_in[0];
    const float* beta = (const float*)d_in[1];
    const float* du   = (const float*)d_in[2];
    const float* di   = (const float*)d_in[3];
    const int*   u    = (const int*)d_in[4];
    const int*   i    = (const int*)d_in[5];
    float* out = (float*)d_out;

    char* ws = (char*)d_ws;

    if (ws_size < (size_t)WS_NEED) {
        // ---------- fallback: proven atomic path ----------
        float* invn = (float*)ws;  // 600 KB
        hipMemsetAsync(d_out, 0, (size_t)out_size * sizeof(float), stream);
        {
            int grid = (NR + 3) / 4;
            norm_kernel<<<grid, 256, 0, stream>>>(x, invn, NR);
        }
        {
            int grid = (N_EDGES + 3) / 4;
            edge_kernel<<<grid, 256, 0, stream>>>(x, beta, du, di, u, i, invn, out);
        }
        return;
    }

    float4* scal  = (float4*)(ws + SCAL_OFF);
    int*    cnt   = (int*)(ws + CNT_OFF);
    int*    off   = (int*)(ws + OFF_OFF);
    int*    cur   = (int*)(ws + CUR_OFF);
    int*    bsum  = (int*)(ws + BSUM_OFF);
    int*    slots = (int*)(ws + SLOT_OFF);

    const int NB = (NR + 1023) / 1024;   // 147 scan blocks

    // 1. per-row scalars (invn, rsqrt(deg), beta)
    scal_kernel<<<(NR + 3) / 4, 256, 0, stream>>>(x, beta, du, di, scal);

    // 2. degree histogram
    hipMemsetAsync(cnt, 0, (size_t)NR * sizeof(int), stream);
    count_kernel<<<(N_EDGES + 255) / 256, 256, 0, stream>>>(u, i, cnt);

    // 3. exclusive scan -> row offsets (+ cursor copy)
    scanA_kernel<<<NB, 1024, 0, stream>>>(cnt, off, bsum, NR);
    scanB_kernel<<<1, 256, 0, stream>>>(bsum, NB);
    scanC_kernel<<<(NR + 255) / 256, 256, 0, stream>>>(off, cur, bsum, NR);

    // 4. fill combined adjacency
    fill_kernel<<<(N_EDGES + 255) / 256, 256, 0, stream>>>(u, i, cur, slots);

    // 5. gather (writes every output row; no memset of d_out needed)
    gather_kernel<<<(NR + 3) / 4, 256, 0, stream>>>(x, scal, off, slots, out);
}

// Round 3
// 541.009 us; speedup vs baseline: 1.7601x; 1.7601x over previous
//
#include <hip/hip_runtime.h>
#include <math.h>

#define N_USERS 100000
#define N_ITEMS 50000
#define NR      150000
#define N_EDGES 2000000
#define D       64
#define EPS     1e-12f

// ---------------- workspace layout (bytes) ----------------
// scal   : float4[NR]      @ 0           2,400,000
// head   : int[NR]         @ 2,400,000     600,000
// next_u : int[N_EDGES]    @ 3,000,000   8,000,000
// next_i : int[N_EDGES]    @ 11,000,000  8,000,000
#define SCAL_OFF  0u
#define HEAD_OFF  2400000u
#define NXTU_OFF  3000000u
#define NXTI_OFF  11000000u
#define WS_NEED   19000000u

// ---------------------------------------------------------------------------
// Per-row scalars: scal[r] = { invn, rsqrt(deg), beta_or_0, 0 }
// ---------------------------------------------------------------------------
__global__ void scal_kernel(const float* __restrict__ x,
                            const float* __restrict__ beta,
                            const float* __restrict__ du,
                            const float* __restrict__ di,
                            float4* __restrict__ scal) {
    int gid  = blockIdx.x * blockDim.x + threadIdx.x;
    int r    = gid >> 6;
    int lane = gid & 63;
    if (r >= NR) return;

    float v  = x[r * D + lane];
    float ss = v * v;
    #pragma unroll
    for (int m = 32; m >= 1; m >>= 1) ss += __shfl_xor(ss, m);

    if (lane == 0) {
        float invn = 1.0f / fmaxf(sqrtf(ss), EPS);
        float deg  = (r < N_USERS) ? du[r] : di[r - N_USERS];
        float b    = (r < N_USERS) ? beta[r] : 0.0f;
        scal[r] = make_float4(invn, rsqrtf(deg), b, 0.0f);
    }
}

// ---------------------------------------------------------------------------
// Lock-free per-row linked lists (prepend). All next-stores coalesced by e.
// ---------------------------------------------------------------------------
__global__ void link_kernel(const int* __restrict__ u,
                            const int* __restrict__ i,
                            int* __restrict__ head,
                            int* __restrict__ next_u,
                            int* __restrict__ next_i) {
    int e = blockIdx.x * blockDim.x + threadIdx.x;
    if (e >= N_EDGES) return;
    int uu = u[e];
    int ii = N_USERS + i[e];
    next_u[e] = atomicExch(&head[uu], e);
    next_i[e] = atomicExch(&head[ii], e);
}

// ---------------------------------------------------------------------------
// Gather, transposed: one wave per row; 4 neighbors per iteration.
// lane = (g = lane>>4 : neighbor slot, q = lane&15 : dim quarter).
// Chain walk for batch k+1 is issued before compute of batch k (1-deep pipe).
// ---------------------------------------------------------------------------
__global__ void gather_kernel(const float4* __restrict__ x4,    // [NR*16]
                              const float4* __restrict__ scal,
                              const int* __restrict__ head,
                              const int* __restrict__ next_u,
                              const int* __restrict__ next_i,
                              const int* __restrict__ u,
                              const int* __restrict__ i,
                              float4* __restrict__ out4) {
    int gid  = blockIdx.x * blockDim.x + threadIdx.x;
    int r    = gid >> 6;
    int lane = gid & 63;
    if (r >= NR) return;

    int g = lane >> 4;       // neighbor slot within batch
    int q = lane & 15;       // dim quarter (dims 4q..4q+3)

    bool isu = (r < N_USERS);
    const int* __restrict__ nxt = isu ? next_u : next_i;
    const int* __restrict__ oid = isu ? i : u;      // other-side raw id
    int obase = isu ? N_USERS : 0;

    float4 sc = scal[r];
    float4 xs = x4[r * 16 + q];

    float4 acc = make_float4(0.f, 0.f, 0.f, 0.f);

    // ---- collect first batch (wave-uniform serial chain walk) ----
    int e  = head[r];
    int c0 = e;
    { int t = nxt[(c0 >= 0) ? c0 : 0]; e = (c0 >= 0) ? t : -1; }
    int c1 = e;
    { int t = nxt[(c1 >= 0) ? c1 : 0]; e = (c1 >= 0) ? t : -1; }
    int c2 = e;
    { int t = nxt[(c2 >= 0) ? c2 : 0]; e = (c2 >= 0) ? t : -1; }
    int c3 = e;
    { int t = nxt[(c3 >= 0) ? c3 : 0]; e = (c3 >= 0) ? t : -1; }

    while (c0 >= 0) {
        // ---- prefetch next batch's chain (independent of compute below) ----
        int n0 = e;
        { int t = nxt[(n0 >= 0) ? n0 : 0]; e = (n0 >= 0) ? t : -1; }
        int n1 = e;
        { int t = nxt[(n1 >= 0) ? n1 : 0]; e = (n1 >= 0) ? t : -1; }
        int n2 = e;
        { int t = nxt[(n2 >= 0) ? n2 : 0]; e = (n2 >= 0) ? t : -1; }
        int n3 = e;
        { int t = nxt[(n3 >= 0) ? n3 : 0]; e = (n3 >= 0) ? t : -1; }

        // ---- compute current batch ----
        int eg = (g == 0) ? c0 : (g == 1) ? c1 : (g == 2) ? c2 : c3;
        bool valid = (eg >= 0);
        int  es = valid ? eg : c0;              // c0 >= 0 inside loop
        int  nb = obase + oid[es];              // neighbor row index

        float4 so = scal[nb];
        float4 xo = x4[nb * 16 + q];

        float p = xs.x * xo.x + xs.y * xo.y + xs.z * xo.z + xs.w * xo.w;
        p += __shfl_xor(p, 1);
        p += __shfl_xor(p, 2);
        p += __shfl_xor(p, 4);
        p += __shfl_xor(p, 8);                  // full dot within 16-lane group

        float b   = isu ? sc.z : so.z;
        float sv  = p * sc.x * so.x - b;
        float sig = 1.0f / (1.0f + __expf(-sv));
        float w   = 4.0f * sig * (1.0f - sig) * sc.y * so.y;
        w = valid ? w : 0.0f;

        acc.x = fmaf(w, xo.x, acc.x);
        acc.y = fmaf(w, xo.y, acc.y);
        acc.z = fmaf(w, xo.z, acc.z);
        acc.w = fmaf(w, xo.w, acc.w);

        c0 = n0; c1 = n1; c2 = n2; c3 = n3;
    }

    // ---- reduce partial accumulators across the 4 groups ----
    acc.x += __shfl_xor(acc.x, 16); acc.y += __shfl_xor(acc.y, 16);
    acc.z += __shfl_xor(acc.z, 16); acc.w += __shfl_xor(acc.w, 16);
    acc.x += __shfl_xor(acc.x, 32); acc.y += __shfl_xor(acc.y, 32);
    acc.z += __shfl_xor(acc.z, 32); acc.w += __shfl_xor(acc.w, 32);

    if (g == 0) out4[r * 16 + q] = acc;         // 256 B coalesced store
}

// ---------------------------------------------------------------------------
// Fallback (round-1 proven path) if workspace is too small
// ---------------------------------------------------------------------------
__global__ void norm_kernel(const float* __restrict__ x,
                            float* __restrict__ invn,
                            int nrows) {
    int gid  = blockIdx.x * blockDim.x + threadIdx.x;
    int wave = gid >> 6;
    int lane = gid & 63;
    if (wave >= nrows) return;
    float v  = x[wave * D + lane];
    float ss = v * v;
    #pragma unroll
    for (int m = 32; m >= 1; m >>= 1) ss += __shfl_xor(ss, m);
    if (lane == 0) invn[wave] = 1.0f / fmaxf(sqrtf(ss), EPS);
}

__global__ void edge_kernel(const float* __restrict__ x,
                            const float* __restrict__ beta,
                            const float* __restrict__ du,
                            const float* __restrict__ di,
                            const int*   __restrict__ u,
                            const int*   __restrict__ i,
                            const float* __restrict__ invn,
                            float* __restrict__ out) {
    int gid  = blockIdx.x * blockDim.x + threadIdx.x;
    int wave = gid >> 6;
    int lane = gid & 63;
    if (wave >= N_EDGES) return;
    int uu = u[wave];
    int ii = i[wave];
    const float xu = x[uu * D + lane];
    const float xi = x[(N_USERS + ii) * D + lane];
    float p = xu * xi;
    #pragma unroll
    for (int m = 32; m >= 1; m >>= 1) p += __shfl_xor(p, m);
    float s   = p * invn[uu] * invn[N_USERS + ii] - beta[uu];
    float sig = 1.0f / (1.0f + __expf(-s));
    float w   = 4.0f * sig * (1.0f - sig) * rsqrtf(du[uu]) * rsqrtf(di[ii]);
    atomicAdd(&out[uu * D + lane],             w * xi);
    atomicAdd(&out[(N_USERS + ii) * D + lane], w * xu);
}

// ---------------------------------------------------------------------------
extern "C" void kernel_launch(void* const* d_in, const int* in_sizes, int n_in,
                              void* d_out, int out_size, void* d_ws, size_t ws_size,
                              hipStream_t stream) {
    const float* x    = (const float*)d_in[0];
    const float* beta = (const float*)d_in[1];
    const float* du   = (const float*)d_in[2];
    const float* di   = (const float*)d_in[3];
    const int*   u    = (const int*)d_in[4];
    const int*   i    = (const int*)d_in[5];
    float* out = (float*)d_out;

    char* ws = (char*)d_ws;

    if (ws_size < (size_t)WS_NEED) {
        // ---------- fallback: proven atomic path ----------
        float* invn = (float*)ws;
        hipMemsetAsync(d_out, 0, (size_t)out_size * sizeof(float), stream);
        norm_kernel<<<(NR + 3) / 4, 256, 0, stream>>>(x, invn, NR);
        edge_kernel<<<(N_EDGES + 3) / 4, 256, 0, stream>>>(x, beta, du, di, u, i, invn, out);
        return;
    }

    float4* scal   = (float4*)(ws + SCAL_OFF);
    int*    head   = (int*)(ws + HEAD_OFF);
    int*    next_u = (int*)(ws + NXTU_OFF);
    int*    next_i = (int*)(ws + NXTI_OFF);

    // 1. per-row scalars
    scal_kernel<<<(NR + 3) / 4, 256, 0, stream>>>(x, beta, du, di, scal);

    // 2. head = -1
    hipMemsetAsync(head, 0xFF, (size_t)NR * sizeof(int), stream);

    // 3. build per-row linked lists (one edge-parallel pass)
    link_kernel<<<(N_EDGES + 255) / 256, 256, 0, stream>>>(u, i, head, next_u, next_i);

    // 4. gather (writes every output row)
    gather_kernel<<<(NR + 3) / 4, 256, 0, stream>>>((const float4*)x, scal, head,
                                                    next_u, next_i, u, i,
                                                    (float4*)out);
}

// Round 4
// 539.463 us; speedup vs baseline: 1.7651x; 1.0029x over previous
//
#include <hip/hip_runtime.h>
#include <math.h>

#define N_USERS 100000
#define N_ITEMS 50000
#define NR      150000
#define N_EDGES 2000000
#define D       64
#define EPS     1e-12f

// ---------------- Tier-A workspace layout (bytes) ----------------
// scal  : float4[NR]        @ 0            2,400,000
// xh    : ushort[NR*64]     @ 2,400,000   19,200,000
// head  : int[NR]           @ 21,600,000     600,000
// rec_u : int2[N_EDGES]     @ 22,200,000  16,000,000
// rec_i : int2[N_EDGES]     @ 38,200,000  16,000,000
#define SCAL_OFF 0u
#define XH_OFF   2400000u
#define HEAD_OFF 21600000u
#define RECU_OFF 22200000u
#define RECI_OFF 38200000u
#define WS_A     54200000u

// ---------------- Tier-C (round-3 proven) layout ----------------
#define C_SCAL 0u
#define C_HEAD 2400000u
#define C_NXTU 3000000u
#define C_NXTI 11000000u
#define WS_C   19000000u

__device__ __forceinline__ unsigned short f2bf(float v) {
    unsigned int b = __float_as_uint(v);
    b += 0x7FFFu + ((b >> 16) & 1u);          // round-to-nearest-even
    return (unsigned short)(b >> 16);
}
#define BF_LO(w) __uint_as_float((w) << 16)
#define BF_HI(w) __uint_as_float((w) & 0xFFFF0000u)

// ---------------------------------------------------------------------------
// Tier A kernel 1: per-row scalars + bf16 copy of x.
// ---------------------------------------------------------------------------
__global__ void prep_kernel(const float* __restrict__ x,
                            const float* __restrict__ beta,
                            const float* __restrict__ du,
                            const float* __restrict__ di,
                            float4* __restrict__ scal,
                            unsigned short* __restrict__ xh) {
    int gid  = blockIdx.x * blockDim.x + threadIdx.x;
    int r    = gid >> 6;
    int lane = gid & 63;
    if (r >= NR) return;

    float v = x[r * D + lane];
    xh[r * D + lane] = f2bf(v);

    float ss = v * v;
    #pragma unroll
    for (int m = 32; m >= 1; m >>= 1) ss += __shfl_xor(ss, m);

    if (lane == 0) {
        float invn = 1.0f / fmaxf(sqrtf(ss), EPS);
        float deg  = (r < N_USERS) ? du[r] : di[r - N_USERS];
        float b    = (r < N_USERS) ? beta[r] : 0.0f;
        scal[r] = make_float4(invn, rsqrtf(deg), b, 0.0f);
    }
}

// ---------------------------------------------------------------------------
// Tier A kernel 2: lock-free per-row linked lists with packed neighbor id.
// rec[e] = { next_edge_in_this_row's_chain, neighbor_row_index }
// ---------------------------------------------------------------------------
__global__ void link2_kernel(const int* __restrict__ u,
                             const int* __restrict__ i,
                             int* __restrict__ head,
                             int2* __restrict__ rec_u,
                             int2* __restrict__ rec_i) {
    int e = blockIdx.x * blockDim.x + threadIdx.x;
    if (e >= N_EDGES) return;
    int uu = u[e];
    int ii = N_USERS + i[e];
    rec_u[e] = make_int2(atomicExch(&head[uu], e), ii);
    rec_i[e] = make_int2(atomicExch(&head[ii], e), uu);
}

// ---------------------------------------------------------------------------
// Tier A kernel 3: gather, 8 neighbors per wave-iteration.
// lane = (g = lane>>3 : neighbor slot, q = lane&7 : dim octet 8q..8q+7).
// Chain records are int2 {next, nbr}; rows read as bf16 (16 B per lane).
// ---------------------------------------------------------------------------
__global__ void gather8_kernel(const unsigned short* __restrict__ xh,
                               const float4* __restrict__ scal,
                               const int* __restrict__ head,
                               const int2* __restrict__ rec_u,
                               const int2* __restrict__ rec_i,
                               float* __restrict__ out) {
    int gid  = blockIdx.x * blockDim.x + threadIdx.x;
    int r    = gid >> 6;
    int lane = gid & 63;
    if (r >= NR) return;

    int g = lane >> 3;
    int q = lane & 7;
    bool isu = (r < N_USERS);
    const int2* __restrict__ rec = isu ? rec_u : rec_i;

    float4 sc = scal[r];
    uint4 hs = *(const uint4*)(xh + (size_t)r * D + q * 8);
    float xs0 = BF_LO(hs.x), xs1 = BF_HI(hs.x);
    float xs2 = BF_LO(hs.y), xs3 = BF_HI(hs.y);
    float xs4 = BF_LO(hs.z), xs5 = BF_HI(hs.z);
    float xs6 = BF_LO(hs.w), xs7 = BF_HI(hs.w);

    float a0=0.f,a1=0.f,a2=0.f,a3=0.f,a4=0.f,a5=0.f,a6=0.f,a7=0.f;

    // walk step: consume cursor e, produce one slot's neighbor (-1 invalid)
#define STEP(dst) { bool v_ = (e >= 0); int2 t_ = rec[v_ ? e : 0]; \
                    dst = v_ ? t_.y : -1; e = v_ ? t_.x : -1; }

    int e = head[r];
    int nb0,nb1,nb2,nb3,nb4,nb5,nb6,nb7;
    STEP(nb0) STEP(nb1) STEP(nb2) STEP(nb3)
    STEP(nb4) STEP(nb5) STEP(nb6) STEP(nb7)

    while (nb0 >= 0) {
        // ---- prefetch next batch's chain (independent of compute) ----
        int m0,m1,m2,m3,m4,m5,m6,m7;
        STEP(m0) STEP(m1) STEP(m2) STEP(m3)
        STEP(m4) STEP(m5) STEP(m6) STEP(m7)

        // ---- select this group's neighbor (ternary tree on g bits) ----
        int t01 = (g & 1) ? nb1 : nb0;
        int t23 = (g & 1) ? nb3 : nb2;
        int t45 = (g & 1) ? nb5 : nb4;
        int t67 = (g & 1) ? nb7 : nb6;
        int t03 = (g & 2) ? t23 : t01;
        int t47 = (g & 2) ? t67 : t45;
        int sel = (g & 4) ? t47 : t03;
        bool valid = (sel >= 0);
        int  nb = valid ? sel : nb0;            // nb0 >= 0 inside loop

        float4 so = scal[nb];
        uint4 ho = *(const uint4*)(xh + (size_t)nb * D + q * 8);
        float o0 = BF_LO(ho.x), o1 = BF_HI(ho.x);
        float o2 = BF_LO(ho.y), o3 = BF_HI(ho.y);
        float o4 = BF_LO(ho.z), o5 = BF_HI(ho.z);
        float o6 = BF_LO(ho.w), o7 = BF_HI(ho.w);

        float p = xs0*o0 + xs1*o1 + xs2*o2 + xs3*o3
                + xs4*o4 + xs5*o5 + xs6*o6 + xs7*o7;
        p += __shfl_xor(p, 1);
        p += __shfl_xor(p, 2);
        p += __shfl_xor(p, 4);                  // full dot within 8-lane group

        float b   = isu ? sc.z : so.z;
        float sv  = p * sc.x * so.x - b;
        float sig = 1.0f / (1.0f + __expf(-sv));
        float w   = 4.0f * sig * (1.0f - sig) * sc.y * so.y;
        w = valid ? w : 0.0f;

        a0 = fmaf(w, o0, a0); a1 = fmaf(w, o1, a1);
        a2 = fmaf(w, o2, a2); a3 = fmaf(w, o3, a3);
        a4 = fmaf(w, o4, a4); a5 = fmaf(w, o5, a5);
        a6 = fmaf(w, o6, a6); a7 = fmaf(w, o7, a7);

        nb0=m0; nb1=m1; nb2=m2; nb3=m3; nb4=m4; nb5=m5; nb6=m6; nb7=m7;
    }
#undef STEP

    // ---- reduce partial accumulators across the 8 groups ----
    #pragma unroll
    for (int m = 8; m <= 32; m <<= 1) {
        a0 += __shfl_xor(a0, m); a1 += __shfl_xor(a1, m);
        a2 += __shfl_xor(a2, m); a3 += __shfl_xor(a3, m);
        a4 += __shfl_xor(a4, m); a5 += __shfl_xor(a5, m);
        a6 += __shfl_xor(a6, m); a7 += __shfl_xor(a7, m);
    }

    if (g == 0) {
        float4* o4p = (float4*)(out + (size_t)r * D + q * 8);
        o4p[0] = make_float4(a0, a1, a2, a3);
        o4p[1] = make_float4(a4, a5, a6, a7);
    }
}

// ---------------------------------------------------------------------------
// Tier C (round-3 proven path)
// ---------------------------------------------------------------------------
__global__ void scal_kernel(const float* __restrict__ x,
                            const float* __restrict__ beta,
                            const float* __restrict__ du,
                            const float* __restrict__ di,
                            float4* __restrict__ scal) {
    int gid  = blockIdx.x * blockDim.x + threadIdx.x;
    int r    = gid >> 6;
    int lane = gid & 63;
    if (r >= NR) return;
    float v  = x[r * D + lane];
    float ss = v * v;
    #pragma unroll
    for (int m = 32; m >= 1; m >>= 1) ss += __shfl_xor(ss, m);
    if (lane == 0) {
        float invn = 1.0f / fmaxf(sqrtf(ss), EPS);
        float deg  = (r < N_USERS) ? du[r] : di[r - N_USERS];
        float b    = (r < N_USERS) ? beta[r] : 0.0f;
        scal[r] = make_float4(invn, rsqrtf(deg), b, 0.0f);
    }
}

__global__ void link_kernel(const int* __restrict__ u,
                            const int* __restrict__ i,
                            int* __restrict__ head,
                            int* __restrict__ next_u,
                            int* __restrict__ next_i) {
    int e = blockIdx.x * blockDim.x + threadIdx.x;
    if (e >= N_EDGES) return;
    int uu = u[e];
    int ii = N_USERS + i[e];
    next_u[e] = atomicExch(&head[uu], e);
    next_i[e] = atomicExch(&head[ii], e);
}

__global__ void gather_kernel(const float4* __restrict__ x4,
                              const float4* __restrict__ scal,
                              const int* __restrict__ head,
                              const int* __restrict__ next_u,
                              const int* __restrict__ next_i,
                              const int* __restrict__ u,
                              const int* __restrict__ i,
                              float4* __restrict__ out4) {
    int gid  = blockIdx.x * blockDim.x + threadIdx.x;
    int r    = gid >> 6;
    int lane = gid & 63;
    if (r >= NR) return;
    int g = lane >> 4;
    int q = lane & 15;
    bool isu = (r < N_USERS);
    const int* __restrict__ nxt = isu ? next_u : next_i;
    const int* __restrict__ oid = isu ? i : u;
    int obase = isu ? N_USERS : 0;
    float4 sc = scal[r];
    float4 xs = x4[r * 16 + q];
    float4 acc = make_float4(0.f, 0.f, 0.f, 0.f);
    int e  = head[r];
    int c0 = e; { int t = nxt[(c0 >= 0) ? c0 : 0]; e = (c0 >= 0) ? t : -1; }
    int c1 = e; { int t = nxt[(c1 >= 0) ? c1 : 0]; e = (c1 >= 0) ? t : -1; }
    int c2 = e; { int t = nxt[(c2 >= 0) ? c2 : 0]; e = (c2 >= 0) ? t : -1; }
    int c3 = e; { int t = nxt[(c3 >= 0) ? c3 : 0]; e = (c3 >= 0) ? t : -1; }
    while (c0 >= 0) {
        int n0 = e; { int t = nxt[(n0 >= 0) ? n0 : 0]; e = (n0 >= 0) ? t : -1; }
        int n1 = e; { int t = nxt[(n1 >= 0) ? n1 : 0]; e = (n1 >= 0) ? t : -1; }
        int n2 = e; { int t = nxt[(n2 >= 0) ? n2 : 0]; e = (n2 >= 0) ? t : -1; }
        int n3 = e; { int t = nxt[(n3 >= 0) ? n3 : 0]; e = (n3 >= 0) ? t : -1; }
        int eg = (g == 0) ? c0 : (g == 1) ? c1 : (g == 2) ? c2 : c3;
        bool valid = (eg >= 0);
        int  es = valid ? eg : c0;
        int  nb = obase + oid[es];
        float4 so = scal[nb];
        float4 xo = x4[nb * 16 + q];
        float p = xs.x * xo.x + xs.y * xo.y + xs.z * xo.z + xs.w * xo.w;
        p += __shfl_xor(p, 1);
        p += __shfl_xor(p, 2);
        p += __shfl_xor(p, 4);
        p += __shfl_xor(p, 8);
        float b   = isu ? sc.z : so.z;
        float sv  = p * sc.x * so.x - b;
        float sig = 1.0f / (1.0f + __expf(-sv));
        float w   = 4.0f * sig * (1.0f - sig) * sc.y * so.y;
        w = valid ? w : 0.0f;
        acc.x = fmaf(w, xo.x, acc.x);
        acc.y = fmaf(w, xo.y, acc.y);
        acc.z = fmaf(w, xo.z, acc.z);
        acc.w = fmaf(w, xo.w, acc.w);
        c0 = n0; c1 = n1; c2 = n2; c3 = n3;
    }
    acc.x += __shfl_xor(acc.x, 16); acc.y += __shfl_xor(acc.y, 16);
    acc.z += __shfl_xor(acc.z, 16); acc.w += __shfl_xor(acc.w, 16);
    acc.x += __shfl_xor(acc.x, 32); acc.y += __shfl_xor(acc.y, 32);
    acc.z += __shfl_xor(acc.z, 32); acc.w += __shfl_xor(acc.w, 32);
    if (g == 0) out4[r * 16 + q] = acc;
}

// ---------------------------------------------------------------------------
// Tier D (round-1 atomic fallback)
// ---------------------------------------------------------------------------
__global__ void norm_kernel(const float* __restrict__ x,
                            float* __restrict__ invn,
                            int nrows) {
    int gid  = blockIdx.x * blockDim.x + threadIdx.x;
    int wave = gid >> 6;
    int lane = gid & 63;
    if (wave >= nrows) return;
    float v  = x[wave * D + lane];
    float ss = v * v;
    #pragma unroll
    for (int m = 32; m >= 1; m >>= 1) ss += __shfl_xor(ss, m);
    if (lane == 0) invn[wave] = 1.0f / fmaxf(sqrtf(ss), EPS);
}

__global__ void edge_kernel(const float* __restrict__ x,
                            const float* __restrict__ beta,
                            const float* __restrict__ du,
                            const float* __restrict__ di,
                            const int*   __restrict__ u,
                            const int*   __restrict__ i,
                            const float* __restrict__ invn,
                            float* __restrict__ out) {
    int gid  = blockIdx.x * blockDim.x + threadIdx.x;
    int wave = gid >> 6;
    int lane = gid & 63;
    if (wave >= N_EDGES) return;
    int uu = u[wave];
    int ii = i[wave];
    const float xu = x[uu * D + lane];
    const float xi = x[(N_USERS + ii) * D + lane];
    float p = xu * xi;
    #pragma unroll
    for (int m = 32; m >= 1; m >>= 1) p += __shfl_xor(p, m);
    float s   = p * invn[uu] * invn[N_USERS + ii] - beta[uu];
    float sig = 1.0f / (1.0f + __expf(-s));
    float w   = 4.0f * sig * (1.0f - sig) * rsqrtf(du[uu]) * rsqrtf(di[ii]);
    atomicAdd(&out[uu * D + lane],             w * xi);
    atomicAdd(&out[(N_USERS + ii) * D + lane], w * xu);
}

// ---------------------------------------------------------------------------
extern "C" void kernel_launch(void* const* d_in, const int* in_sizes, int n_in,
                              void* d_out, int out_size, void* d_ws, size_t ws_size,
                              hipStream_t stream) {
    const float* x    = (const float*)d_in[0];
    const float* beta = (const float*)d_in[1];
    const float* du   = (const float*)d_in[2];
    const float* di   = (const float*)d_in[3];
    const int*   u    = (const int*)d_in[4];
    const int*   i    = (const int*)d_in[5];
    float* out = (float*)d_out;
    char*  ws  = (char*)d_ws;

    if (ws_size >= (size_t)WS_A) {
        float4*         scal  = (float4*)(ws + SCAL_OFF);
        unsigned short* xh    = (unsigned short*)(ws + XH_OFF);
        int*            head  = (int*)(ws + HEAD_OFF);
        int2*           rec_u = (int2*)(ws + RECU_OFF);
        int2*           rec_i = (int2*)(ws + RECI_OFF);

        prep_kernel<<<(NR + 3) / 4, 256, 0, stream>>>(x, beta, du, di, scal, xh);
        hipMemsetAsync(head, 0xFF, (size_t)NR * sizeof(int), stream);
        link2_kernel<<<(N_EDGES + 255) / 256, 256, 0, stream>>>(u, i, head, rec_u, rec_i);
        gather8_kernel<<<(NR + 3) / 4, 256, 0, stream>>>(xh, scal, head, rec_u, rec_i, out);
    } else if (ws_size >= (size_t)WS_C) {
        float4* scal   = (float4*)(ws + C_SCAL);
        int*    head   = (int*)(ws + C_HEAD);
        int*    next_u = (int*)(ws + C_NXTU);
        int*    next_i = (int*)(ws + C_NXTI);

        scal_kernel<<<(NR + 3) / 4, 256, 0, stream>>>(x, beta, du, di, scal);
        hipMemsetAsync(head, 0xFF, (size_t)NR * sizeof(int), stream);
        link_kernel<<<(N_EDGES + 255) / 256, 256, 0, stream>>>(u, i, head, next_u, next_i);
        gather_kernel<<<(NR + 3) / 4, 256, 0, stream>>>((const float4*)x, scal, head,
                                                        next_u, next_i, u, i, (float4*)out);
    } else {
        float* invn = (float*)ws;
        hipMemsetAsync(d_out, 0, (size_t)out_size * sizeof(float), stream);
        norm_kernel<<<(NR + 3) / 4, 256, 0, stream>>>(x, invn, NR);
        edge_kernel<<<(N_EDGES + 3) / 4, 256, 0, stream>>>(x, beta, du, di, u, i, invn, out);
    }
}

// Round 5
// 508.076 us; speedup vs baseline: 1.8741x; 1.0618x over previous
//
#include <hip/hip_runtime.h>
#include <math.h>

#define N_USERS 100000
#define N_ITEMS 50000
#define NR      150000
#define N_EDGES 2000000
#define D       64
#define EPS     1e-12f

#define UPAD 64      // user bucket capacity  (deg ~ Poisson(20))
#define IPAD 94      // item bucket capacity  (deg ~ Poisson(40))
#define OVF_CAP 1024

// ---------------- Tier-A2 workspace layout (bytes) ----------------
// scal : float4[NR]              @ 0             2,400,000
// xh   : ushort[NR*64]           @ 2,400,000    19,200,000
// cnt  : int[NR]                 @ 21,600,000      600,000
// ubkt : u16[N_USERS*UPAD]       @ 22,200,000   12,800,000
// ibkt : u32[N_ITEMS*IPAD]       @ 35,000,000   18,800,000
// ovfc : int                     @ 53,800,000            4
// ovf  : int[OVF_CAP]            @ 53,800,004        4,096
#define SCAL_OFF 0u
#define XH_OFF   2400000u
#define CNT_OFF  21600000u
#define UBKT_OFF 22200000u
#define IBKT_OFF 35000000u
#define OVFC_OFF 53800000u
#define OVF_OFF  53800004u
#define WS_A2    53804100u

// ---------------- Tier-C (round-3 proven) layout ----------------
#define C_SCAL 0u
#define C_HEAD 2400000u
#define C_NXTU 3000000u
#define C_NXTI 11000000u
#define WS_C   19000000u

__device__ __forceinline__ unsigned short f2bf(float v) {
    unsigned int b = __float_as_uint(v);
    b += 0x7FFFu + ((b >> 16) & 1u);          // round-to-nearest-even
    return (unsigned short)(b >> 16);
}
#define BF_LO(w) __uint_as_float((w) << 16)
#define BF_HI(w) __uint_as_float((w) & 0xFFFF0000u)

// ---------------------------------------------------------------------------
// Per-row scalars + bf16 copy of x.  scal[r] = {invn, rsqrt(deg), beta, 0}
// ---------------------------------------------------------------------------
__global__ void prep_kernel(const float* __restrict__ x,
                            const float* __restrict__ beta,
                            const float* __restrict__ du,
                            const float* __restrict__ di,
                            float4* __restrict__ scal,
                            unsigned short* __restrict__ xh) {
    int gid  = blockIdx.x * blockDim.x + threadIdx.x;
    int r    = gid >> 6;
    int lane = gid & 63;
    if (r >= NR) return;

    float v = x[r * D + lane];
    xh[r * D + lane] = f2bf(v);

    float ss = v * v;
    #pragma unroll
    for (int m = 32; m >= 1; m >>= 1) ss += __shfl_xor(ss, m);

    if (lane == 0) {
        float invn = 1.0f / fmaxf(sqrtf(ss), EPS);
        float deg  = (r < N_USERS) ? du[r] : di[r - N_USERS];
        float b    = (r < N_USERS) ? beta[r] : 0.0f;
        scal[r] = make_float4(invn, rsqrtf(deg), b, 0.0f);
    }
}

// ---------------------------------------------------------------------------
// One-pass direct-slot bucket fill (single atomic pass, chase-free result).
// ---------------------------------------------------------------------------
__global__ void fill_kernel(const int* __restrict__ u,
                            const int* __restrict__ i,
                            int* __restrict__ cnt,
                            unsigned short* __restrict__ ubkt,
                            unsigned int* __restrict__ ibkt,
                            int* __restrict__ ovfc,
                            int* __restrict__ ovf) {
    int e = blockIdx.x * blockDim.x + threadIdx.x;
    if (e >= N_EDGES) return;
    int uu = u[e];
    int ii = i[e];

    int su = atomicAdd(&cnt[uu], 1);
    if (su < UPAD) {
        ubkt[(size_t)uu * UPAD + su] = (unsigned short)ii;
    } else {
        int p = atomicAdd(ovfc, 1);
        if (p < OVF_CAP) ovf[p] = (e << 1);
    }

    int si = atomicAdd(&cnt[N_USERS + ii], 1);
    if (si < IPAD) {
        ibkt[(size_t)ii * IPAD + si] = (unsigned int)uu;
    } else {
        int p = atomicAdd(ovfc, 1);
        if (p < OVF_CAP) ovf[p] = (e << 1) | 1;
    }
}

// ---------------------------------------------------------------------------
// Gather for USER rows: wave per row, 8 neighbors/iter from a streamed id
// list (no pointer chase). lane = (g = lane>>3 slot, q = lane&7 dim octet).
// ---------------------------------------------------------------------------
__global__ void gatherU_kernel(const unsigned short* __restrict__ xh,
                               const float4* __restrict__ scal,
                               const int* __restrict__ cnt,
                               const unsigned short* __restrict__ ubkt,
                               float* __restrict__ out) {
    int gid  = blockIdx.x * blockDim.x + threadIdx.x;
    int r    = gid >> 6;
    int lane = gid & 63;
    if (r >= N_USERS) return;

    int g = lane >> 3;
    int q = lane & 7;

    float4 sc = scal[r];
    uint4 hs = *(const uint4*)(xh + (size_t)r * D + q * 8);
    float xs0 = BF_LO(hs.x), xs1 = BF_HI(hs.x);
    float xs2 = BF_LO(hs.y), xs3 = BF_HI(hs.y);
    float xs4 = BF_LO(hs.z), xs5 = BF_HI(hs.z);
    float xs6 = BF_LO(hs.w), xs7 = BF_HI(hs.w);

    int deg = cnt[r];
    if (deg > UPAD) deg = UPAD;
    int iters = (deg + 7) >> 3;

    float a0=0.f,a1=0.f,a2=0.f,a3=0.f,a4=0.f,a5=0.f,a6=0.f,a7=0.f;

    for (int it = 0; it < iters; ++it) {
        int idx = it * 8 + g;
        bool valid = (idx < deg);
        int nb = N_USERS + (int)ubkt[(size_t)r * UPAD + (valid ? idx : 0)];

        float4 so = scal[nb];
        uint4 ho = *(const uint4*)(xh + (size_t)nb * D + q * 8);
        float o0 = BF_LO(ho.x), o1 = BF_HI(ho.x);
        float o2 = BF_LO(ho.y), o3 = BF_HI(ho.y);
        float o4 = BF_LO(ho.z), o5 = BF_HI(ho.z);
        float o6 = BF_LO(ho.w), o7 = BF_HI(ho.w);

        float p = xs0*o0 + xs1*o1 + xs2*o2 + xs3*o3
                + xs4*o4 + xs5*o5 + xs6*o6 + xs7*o7;
        p += __shfl_xor(p, 1);
        p += __shfl_xor(p, 2);
        p += __shfl_xor(p, 4);

        float sv  = p * sc.x * so.x - sc.z;          // own beta
        float sig = 1.0f / (1.0f + __expf(-sv));
        float w   = 4.0f * sig * (1.0f - sig) * sc.y * so.y;
        w = valid ? w : 0.0f;

        a0 = fmaf(w, o0, a0); a1 = fmaf(w, o1, a1);
        a2 = fmaf(w, o2, a2); a3 = fmaf(w, o3, a3);
        a4 = fmaf(w, o4, a4); a5 = fmaf(w, o5, a5);
        a6 = fmaf(w, o6, a6); a7 = fmaf(w, o7, a7);
    }

    #pragma unroll
    for (int m = 8; m <= 32; m <<= 1) {
        a0 += __shfl_xor(a0, m); a1 += __shfl_xor(a1, m);
        a2 += __shfl_xor(a2, m); a3 += __shfl_xor(a3, m);
        a4 += __shfl_xor(a4, m); a5 += __shfl_xor(a5, m);
        a6 += __shfl_xor(a6, m); a7 += __shfl_xor(a7, m);
    }

    if (g == 0) {
        float4* o4p = (float4*)(out + (size_t)r * D + q * 8);
        o4p[0] = make_float4(a0, a1, a2, a3);
        o4p[1] = make_float4(a4, a5, a6, a7);
    }
}

// ---------------------------------------------------------------------------
// Gather for ITEM rows (neighbor = user row; beta comes from the neighbor).
// ---------------------------------------------------------------------------
__global__ void gatherI_kernel(const unsigned short* __restrict__ xh,
                               const float4* __restrict__ scal,
                               const int* __restrict__ cnt,
                               const unsigned int* __restrict__ ibkt,
                               float* __restrict__ out) {
    int gid  = blockIdx.x * blockDim.x + threadIdx.x;
    int ri   = gid >> 6;                 // item index
    int lane = gid & 63;
    if (ri >= N_ITEMS) return;
    int r = N_USERS + ri;                // row index

    int g = lane >> 3;
    int q = lane & 7;

    float4 sc = scal[r];
    uint4 hs = *(const uint4*)(xh + (size_t)r * D + q * 8);
    float xs0 = BF_LO(hs.x), xs1 = BF_HI(hs.x);
    float xs2 = BF_LO(hs.y), xs3 = BF_HI(hs.y);
    float xs4 = BF_LO(hs.z), xs5 = BF_HI(hs.z);
    float xs6 = BF_LO(hs.w), xs7 = BF_HI(hs.w);

    int deg = cnt[r];
    if (deg > IPAD) deg = IPAD;
    int iters = (deg + 7) >> 3;

    float a0=0.f,a1=0.f,a2=0.f,a3=0.f,a4=0.f,a5=0.f,a6=0.f,a7=0.f;

    for (int it = 0; it < iters; ++it) {
        int idx = it * 8 + g;
        bool valid = (idx < deg);
        int nb = (int)ibkt[(size_t)ri * IPAD + (valid ? idx : 0)];

        float4 so = scal[nb];
        uint4 ho = *(const uint4*)(xh + (size_t)nb * D + q * 8);
        float o0 = BF_LO(ho.x), o1 = BF_HI(ho.x);
        float o2 = BF_LO(ho.y), o3 = BF_HI(ho.y);
        float o4 = BF_LO(ho.z), o5 = BF_HI(ho.z);
        float o6 = BF_LO(ho.w), o7 = BF_HI(ho.w);

        float p = xs0*o0 + xs1*o1 + xs2*o2 + xs3*o3
                + xs4*o4 + xs5*o5 + xs6*o6 + xs7*o7;
        p += __shfl_xor(p, 1);
        p += __shfl_xor(p, 2);
        p += __shfl_xor(p, 4);

        float sv  = p * sc.x * so.x - so.z;          // neighbor (user) beta
        float sig = 1.0f / (1.0f + __expf(-sv));
        float w   = 4.0f * sig * (1.0f - sig) * sc.y * so.y;
        w = valid ? w : 0.0f;

        a0 = fmaf(w, o0, a0); a1 = fmaf(w, o1, a1);
        a2 = fmaf(w, o2, a2); a3 = fmaf(w, o3, a3);
        a4 = fmaf(w, o4, a4); a5 = fmaf(w, o5, a5);
        a6 = fmaf(w, o6, a6); a7 = fmaf(w, o7, a7);
    }

    #pragma unroll
    for (int m = 8; m <= 32; m <<= 1) {
        a0 += __shfl_xor(a0, m); a1 += __shfl_xor(a1, m);
        a2 += __shfl_xor(a2, m); a3 += __shfl_xor(a3, m);
        a4 += __shfl_xor(a4, m); a5 += __shfl_xor(a5, m);
        a6 += __shfl_xor(a6, m); a7 += __shfl_xor(a7, m);
    }

    if (g == 0) {
        float4* o4p = (float4*)(out + (size_t)r * D + q * 8);
        o4p[0] = make_float4(a0, a1, a2, a3);
        o4p[1] = make_float4(a4, a5, a6, a7);
    }
}

// ---------------------------------------------------------------------------
// Overflow fixer: recompute w for spilled edges (fp32), atomic-add into the
// overflowed side's row. Normally zero work.
// ---------------------------------------------------------------------------
__global__ void ovf_kernel(const float* __restrict__ x,
                           const float4* __restrict__ scal,
                           const int* __restrict__ u,
                           const int* __restrict__ i,
                           const int* __restrict__ ovfc,
                           const int* __restrict__ ovf,
                           float* __restrict__ out) {
    int n = *ovfc;
    if (n > OVF_CAP) n = OVF_CAP;
    int gid  = blockIdx.x * blockDim.x + threadIdx.x;
    int wave = gid >> 6;
    int lane = gid & 63;
    int nw   = (gridDim.x * blockDim.x) >> 6;

    for (int k = wave; k < n; k += nw) {
        int pk = ovf[k];
        int e = pk >> 1, side = pk & 1;
        int uu = u[e];
        int ir = N_USERS + i[e];
        float xu = x[uu * D + lane];
        float xi = x[ir * D + lane];
        float p = xu * xi;
        #pragma unroll
        for (int m = 32; m >= 1; m >>= 1) p += __shfl_xor(p, m);
        float4 su = scal[uu];
        float4 si = scal[ir];
        float sv  = p * su.x * si.x - su.z;
        float sig = 1.0f / (1.0f + __expf(-sv));
        float w   = 4.0f * sig * (1.0f - sig) * su.y * si.y;
        if (side == 0) atomicAdd(&out[(size_t)uu * D + lane], w * xi);
        else           atomicAdd(&out[(size_t)ir * D + lane], w * xu);
    }
}

// ---------------------------------------------------------------------------
// Tier C (round-3 proven linked-list path)
// ---------------------------------------------------------------------------
__global__ void scal_kernel(const float* __restrict__ x,
                            const float* __restrict__ beta,
                            const float* __restrict__ du,
                            const float* __restrict__ di,
                            float4* __restrict__ scal) {
    int gid  = blockIdx.x * blockDim.x + threadIdx.x;
    int r    = gid >> 6;
    int lane = gid & 63;
    if (r >= NR) return;
    float v  = x[r * D + lane];
    float ss = v * v;
    #pragma unroll
    for (int m = 32; m >= 1; m >>= 1) ss += __shfl_xor(ss, m);
    if (lane == 0) {
        float invn = 1.0f / fmaxf(sqrtf(ss), EPS);
        float deg  = (r < N_USERS) ? du[r] : di[r - N_USERS];
        float b    = (r < N_USERS) ? beta[r] : 0.0f;
        scal[r] = make_float4(invn, rsqrtf(deg), b, 0.0f);
    }
}

__global__ void link_kernel(const int* __restrict__ u,
                            const int* __restrict__ i,
                            int* __restrict__ head,
                            int* __restrict__ next_u,
                            int* __restrict__ next_i) {
    int e = blockIdx.x * blockDim.x + threadIdx.x;
    if (e >= N_EDGES) return;
    int uu = u[e];
    int ii = N_USERS + i[e];
    next_u[e] = atomicExch(&head[uu], e);
    next_i[e] = atomicExch(&head[ii], e);
}

__global__ void gather_kernel(const float4* __restrict__ x4,
                              const float4* __restrict__ scal,
                              const int* __restrict__ head,
                              const int* __restrict__ next_u,
                              const int* __restrict__ next_i,
                              const int* __restrict__ u,
                              const int* __restrict__ i,
                              float4* __restrict__ out4) {
    int gid  = blockIdx.x * blockDim.x + threadIdx.x;
    int r    = gid >> 6;
    int lane = gid & 63;
    if (r >= NR) return;
    int g = lane >> 4;
    int q = lane & 15;
    bool isu = (r < N_USERS);
    const int* __restrict__ nxt = isu ? next_u : next_i;
    const int* __restrict__ oid = isu ? i : u;
    int obase = isu ? N_USERS : 0;
    float4 sc = scal[r];
    float4 xs = x4[r * 16 + q];
    float4 acc = make_float4(0.f, 0.f, 0.f, 0.f);
    int e  = head[r];
    int c0 = e; { int t = nxt[(c0 >= 0) ? c0 : 0]; e = (c0 >= 0) ? t : -1; }
    int c1 = e; { int t = nxt[(c1 >= 0) ? c1 : 0]; e = (c1 >= 0) ? t : -1; }
    int c2 = e; { int t = nxt[(c2 >= 0) ? c2 : 0]; e = (c2 >= 0) ? t : -1; }
    int c3 = e; { int t = nxt[(c3 >= 0) ? c3 : 0]; e = (c3 >= 0) ? t : -1; }
    while (c0 >= 0) {
        int n0 = e; { int t = nxt[(n0 >= 0) ? n0 : 0]; e = (n0 >= 0) ? t : -1; }
        int n1 = e; { int t = nxt[(n1 >= 0) ? n1 : 0]; e = (n1 >= 0) ? t : -1; }
        int n2 = e; { int t = nxt[(n2 >= 0) ? n2 : 0]; e = (n2 >= 0) ? t : -1; }
        int n3 = e; { int t = nxt[(n3 >= 0) ? n3 : 0]; e = (n3 >= 0) ? t : -1; }
        int eg = (g == 0) ? c0 : (g == 1) ? c1 : (g == 2) ? c2 : c3;
        bool valid = (eg >= 0);
        int  es = valid ? eg : c0;
        int  nb = obase + oid[es];
        float4 so = scal[nb];
        float4 xo = x4[nb * 16 + q];
        float p = xs.x * xo.x + xs.y * xo.y + xs.z * xo.z + xs.w * xo.w;
        p += __shfl_xor(p, 1);
        p += __shfl_xor(p, 2);
        p += __shfl_xor(p, 4);
        p += __shfl_xor(p, 8);
        float b   = isu ? sc.z : so.z;
        float sv  = p * sc.x * so.x - b;
        float sig = 1.0f / (1.0f + __expf(-sv));
        float w   = 4.0f * sig * (1.0f - sig) * sc.y * so.y;
        w = valid ? w : 0.0f;
        acc.x = fmaf(w, xo.x, acc.x);
        acc.y = fmaf(w, xo.y, acc.y);
        acc.z = fmaf(w, xo.z, acc.z);
        acc.w = fmaf(w, xo.w, acc.w);
        c0 = n0; c1 = n1; c2 = n2; c3 = n3;
    }
    acc.x += __shfl_xor(acc.x, 16); acc.y += __shfl_xor(acc.y, 16);
    acc.z += __shfl_xor(acc.z, 16); acc.w += __shfl_xor(acc.w, 16);
    acc.x += __shfl_xor(acc.x, 32); acc.y += __shfl_xor(acc.y, 32);
    acc.z += __shfl_xor(acc.z, 32); acc.w += __shfl_xor(acc.w, 32);
    if (g == 0) out4[r * 16 + q] = acc;
}

// ---------------------------------------------------------------------------
// Tier D (round-1 atomic fallback)
// ---------------------------------------------------------------------------
__global__ void norm_kernel(const float* __restrict__ x,
                            float* __restrict__ invn,
                            int nrows) {
    int gid  = blockIdx.x * blockDim.x + threadIdx.x;
    int wave = gid >> 6;
    int lane = gid & 63;
    if (wave >= nrows) return;
    float v  = x[wave * D + lane];
    float ss = v * v;
    #pragma unroll
    for (int m = 32; m >= 1; m >>= 1) ss += __shfl_xor(ss, m);
    if (lane == 0) invn[wave] = 1.0f / fmaxf(sqrtf(ss), EPS);
}

__global__ void edge_kernel(const float* __restrict__ x,
                            const float* __restrict__ beta,
                            const float* __restrict__ du,
                            const float* __restrict__ di,
                            const int*   __restrict__ u,
                            const int*   __restrict__ i,
                            const float* __restrict__ invn,
                            float* __restrict__ out) {
    int gid  = blockIdx.x * blockDim.x + threadIdx.x;
    int wave = gid >> 6;
    int lane = gid & 63;
    if (wave >= N_EDGES) return;
    int uu = u[wave];
    int ii = i[wave];
    const float xu = x[uu * D + lane];
    const float xi = x[(N_USERS + ii) * D + lane];
    float p = xu * xi;
    #pragma unroll
    for (int m = 32; m >= 1; m >>= 1) p += __shfl_xor(p, m);
    float s   = p * invn[uu] * invn[N_USERS + ii] - beta[uu];
    float sig = 1.0f / (1.0f + __expf(-s));
    float w   = 4.0f * sig * (1.0f - sig) * rsqrtf(du[uu]) * rsqrtf(di[ii]);
    atomicAdd(&out[uu * D + lane],             w * xi);
    atomicAdd(&out[(N_USERS + ii) * D + lane], w * xu);
}

// ---------------------------------------------------------------------------
extern "C" void kernel_launch(void* const* d_in, const int* in_sizes, int n_in,
                              void* d_out, int out_size, void* d_ws, size_t ws_size,
                              hipStream_t stream) {
    const float* x    = (const float*)d_in[0];
    const float* beta = (const float*)d_in[1];
    const float* du   = (const float*)d_in[2];
    const float* di   = (const float*)d_in[3];
    const int*   u    = (const int*)d_in[4];
    const int*   i    = (const int*)d_in[5];
    float* out = (float*)d_out;
    char*  ws  = (char*)d_ws;

    if (ws_size >= (size_t)WS_A2) {
        float4*         scal = (float4*)(ws + SCAL_OFF);
        unsigned short* xh   = (unsigned short*)(ws + XH_OFF);
        int*            cnt  = (int*)(ws + CNT_OFF);
        unsigned short* ubkt = (unsigned short*)(ws + UBKT_OFF);
        unsigned int*   ibkt = (unsigned int*)(ws + IBKT_OFF);
        int*            ovfc = (int*)(ws + OVFC_OFF);
        int*            ovf  = (int*)(ws + OVF_OFF);

        prep_kernel<<<(NR + 3) / 4, 256, 0, stream>>>(x, beta, du, di, scal, xh);
        hipMemsetAsync(cnt, 0, (size_t)NR * sizeof(int), stream);
        hipMemsetAsync(ovfc, 0, sizeof(int), stream);
        fill_kernel<<<(N_EDGES + 255) / 256, 256, 0, stream>>>(u, i, cnt, ubkt, ibkt, ovfc, ovf);
        gatherU_kernel<<<(N_USERS + 3) / 4, 256, 0, stream>>>(xh, scal, cnt, ubkt, out);
        gatherI_kernel<<<(N_ITEMS + 3) / 4, 256, 0, stream>>>(xh, scal, cnt, ibkt, out);
        ovf_kernel<<<64, 256, 0, stream>>>(x, scal, u, i, ovfc, ovf, out);
    } else if (ws_size >= (size_t)WS_C) {
        float4* scal   = (float4*)(ws + C_SCAL);
        int*    head   = (int*)(ws + C_HEAD);
        int*    next_u = (int*)(ws + C_NXTU);
        int*    next_i = (int*)(ws + C_NXTI);

        scal_kernel<<<(NR + 3) / 4, 256, 0, stream>>>(x, beta, du, di, scal);
        hipMemsetAsync(head, 0xFF, (size_t)NR * sizeof(int), stream);
        link_kernel<<<(N_EDGES + 255) / 256, 256, 0, stream>>>(u, i, head, next_u, next_i);
        gather_kernel<<<(NR + 3) / 4, 256, 0, stream>>>((const float4*)x, scal, head,
                                                        next_u, next_i, u, i, (float4*)out);
    } else {
        float* invn = (float*)ws;
        hipMemsetAsync(d_out, 0, (size_t)out_size * sizeof(float), stream);
        norm_kernel<<<(NR + 3) / 4, 256, 0, stream>>>(x, invn, NR);
        edge_kernel<<<(N_EDGES + 3) / 4, 256, 0, stream>>>(x, beta, du, di, u, i, invn, out);
    }
}

// Round 6
// 317.559 us; speedup vs baseline: 2.9985x; 1.5999x over previous
//
#include <hip/hip_runtime.h>
#include <math.h>

#define N_USERS 100000
#define N_ITEMS 50000
#define NR      150000
#define N_EDGES 2000000
#define D       64
#define EPS     1e-12f

#define UPAD 64      // user bucket capacity  (deg ~ Poisson(20); P(>64) ~ 1e-13)
#define IPAD 80      // item bucket capacity  (deg ~ Poisson(40); P(>80) ~ 2e-7/row)
#define OVF_CAP 4096

#define NPART 8      // row partitions == XCDs (blockIdx % 8 lands on XCD p)
#define UPP 12500    // user rows per partition
#define IPP 6250     // item rows per partition
#define FILL_BPP 256 // fill blocks per partition (grid = 2048, fully co-resident)

// ---------------- Tier-A3 workspace layout (bytes) ----------------
// scal : float4[NR]              @ 0             2,400,000
// xh   : ushort[NR*64]           @ 2,400,000    19,200,000
// cnt  : int[NR]                 @ 21,600,000      600,000
// ubkt : u16[N_USERS*UPAD]       @ 22,200,000   12,800,000
// ibkt : u32[N_ITEMS*IPAD]       @ 35,000,000   16,000,000
// ovfc : int                     @ 51,000,000            4
// ovf  : int[OVF_CAP]            @ 51,000,004       16,384
#define SCAL_OFF 0u
#define XH_OFF   2400000u
#define CNT_OFF  21600000u
#define UBKT_OFF 22200000u
#define IBKT_OFF 35000000u
#define OVFC_OFF 51000000u
#define OVF_OFF  51000004u
#define WS_A3    51016388u

// ---------------- Tier-C (round-3 proven) layout ----------------
#define C_SCAL 0u
#define C_HEAD 2400000u
#define C_NXTU 3000000u
#define C_NXTI 11000000u
#define WS_C   19000000u

__device__ __forceinline__ unsigned short f2bf(float v) {
    unsigned int b = __float_as_uint(v);
    b += 0x7FFFu + ((b >> 16) & 1u);          // round-to-nearest-even
    return (unsigned short)(b >> 16);
}
#define BF_LO(w) __uint_as_float((w) << 16)
#define BF_HI(w) __uint_as_float((w) & 0xFFFF0000u)

// ---------------------------------------------------------------------------
// Per-row scalars + bf16 copy of x.  scal[r] = {invn, rsqrt(deg), beta, 0}
// ---------------------------------------------------------------------------
__global__ void prep_kernel(const float* __restrict__ x,
                            const float* __restrict__ beta,
                            const float* __restrict__ du,
                            const float* __restrict__ di,
                            float4* __restrict__ scal,
                            unsigned short* __restrict__ xh) {
    int gid  = blockIdx.x * blockDim.x + threadIdx.x;
    int r    = gid >> 6;
    int lane = gid & 63;
    if (r >= NR) return;

    float v = x[r * D + lane];
    xh[r * D + lane] = f2bf(v);

    float ss = v * v;
    #pragma unroll
    for (int m = 32; m >= 1; m >>= 1) ss += __shfl_xor(ss, m);

    if (lane == 0) {
        float invn = 1.0f / fmaxf(sqrtf(ss), EPS);
        float deg  = (r < N_USERS) ? du[r] : di[r - N_USERS];
        float b    = (r < N_USERS) ? beta[r] : 0.0f;
        scal[r] = make_float4(invn, rsqrtf(deg), b, 0.0f);
    }
}

// ---------------------------------------------------------------------------
// XCD-partitioned bucket fill. Blocks with blockIdx%8==p (all on XCD p under
// round-robin dispatch) stream ALL edges (nontemporal) but commit only rows
// in partition p -> bucket+cnt working set (~3.7 MB) stays in XCD p's private
// L2; atomics are L2-local; no cross-XCD dirty-line ping-pong.
// ---------------------------------------------------------------------------
__global__ void fillx_kernel(const int* __restrict__ u,
                             const int* __restrict__ i,
                             int* __restrict__ cnt,
                             unsigned short* __restrict__ ubkt,
                             unsigned int* __restrict__ ibkt,
                             int* __restrict__ ovfc,
                             int* __restrict__ ovf) {
    int p   = blockIdx.x & (NPART - 1);
    int q   = blockIdx.x >> 3;
    int tid = q * blockDim.x + threadIdx.x;
    const int stride = FILL_BPP * 256;

    int ulo = p * UPP, uhi = ulo + UPP;
    int ilo = p * IPP, ihi = ilo + IPP;

    for (int e = tid; e < N_EDGES; e += stride) {
        int uu = __builtin_nontemporal_load(u + e);
        int ii = __builtin_nontemporal_load(i + e);

        if (uu >= ulo && uu < uhi) {
            int s = atomicAdd(&cnt[uu], 1);
            if (s < UPAD) {
                ubkt[(size_t)uu * UPAD + s] = (unsigned short)ii;
            } else {
                int pp = atomicAdd(ovfc, 1);
                if (pp < OVF_CAP) ovf[pp] = (e << 1);
            }
        }
        if (ii >= ilo && ii < ihi) {
            int s = atomicAdd(&cnt[N_USERS + ii], 1);
            if (s < IPAD) {
                ibkt[(size_t)ii * IPAD + s] = (unsigned int)uu;
            } else {
                int pp = atomicAdd(ovfc, 1);
                if (pp < OVF_CAP) ovf[pp] = (e << 1) | 1;
            }
        }
    }
}

// ---------------------------------------------------------------------------
// Gather for USER rows: wave per row, 8 neighbors/iter, chase-free.
// lane = (g = lane>>3 slot, q = lane&7 dim octet).
// ---------------------------------------------------------------------------
__global__ void gatherU_kernel(const unsigned short* __restrict__ xh,
                               const float4* __restrict__ scal,
                               const int* __restrict__ cnt,
                               const unsigned short* __restrict__ ubkt,
                               float* __restrict__ out) {
    int gid  = blockIdx.x * blockDim.x + threadIdx.x;
    int r    = gid >> 6;
    int lane = gid & 63;
    if (r >= N_USERS) return;

    int g = lane >> 3;
    int q = lane & 7;

    float4 sc = scal[r];
    uint4 hs = *(const uint4*)(xh + (size_t)r * D + q * 8);
    float xs0 = BF_LO(hs.x), xs1 = BF_HI(hs.x);
    float xs2 = BF_LO(hs.y), xs3 = BF_HI(hs.y);
    float xs4 = BF_LO(hs.z), xs5 = BF_HI(hs.z);
    float xs6 = BF_LO(hs.w), xs7 = BF_HI(hs.w);

    int deg = cnt[r];
    if (deg > UPAD) deg = UPAD;
    int iters = (deg + 7) >> 3;

    float a0=0.f,a1=0.f,a2=0.f,a3=0.f,a4=0.f,a5=0.f,a6=0.f,a7=0.f;

    for (int it = 0; it < iters; ++it) {
        int idx = it * 8 + g;
        bool valid = (idx < deg);
        int nb = N_USERS + (int)ubkt[(size_t)r * UPAD + (valid ? idx : 0)];

        float4 so = scal[nb];
        uint4 ho = *(const uint4*)(xh + (size_t)nb * D + q * 8);
        float o0 = BF_LO(ho.x), o1 = BF_HI(ho.x);
        float o2 = BF_LO(ho.y), o3 = BF_HI(ho.y);
        float o4 = BF_LO(ho.z), o5 = BF_HI(ho.z);
        float o6 = BF_LO(ho.w), o7 = BF_HI(ho.w);

        float p = xs0*o0 + xs1*o1 + xs2*o2 + xs3*o3
                + xs4*o4 + xs5*o5 + xs6*o6 + xs7*o7;
        p += __shfl_xor(p, 1);
        p += __shfl_xor(p, 2);
        p += __shfl_xor(p, 4);

        float sv  = p * sc.x * so.x - sc.z;          // own beta
        float sig = 1.0f / (1.0f + __expf(-sv));
        float w   = 4.0f * sig * (1.0f - sig) * sc.y * so.y;
        w = valid ? w : 0.0f;

        a0 = fmaf(w, o0, a0); a1 = fmaf(w, o1, a1);
        a2 = fmaf(w, o2, a2); a3 = fmaf(w, o3, a3);
        a4 = fmaf(w, o4, a4); a5 = fmaf(w, o5, a5);
        a6 = fmaf(w, o6, a6); a7 = fmaf(w, o7, a7);
    }

    #pragma unroll
    for (int m = 8; m <= 32; m <<= 1) {
        a0 += __shfl_xor(a0, m); a1 += __shfl_xor(a1, m);
        a2 += __shfl_xor(a2, m); a3 += __shfl_xor(a3, m);
        a4 += __shfl_xor(a4, m); a5 += __shfl_xor(a5, m);
        a6 += __shfl_xor(a6, m); a7 += __shfl_xor(a7, m);
    }

    if (g == 0) {
        float4* o4p = (float4*)(out + (size_t)r * D + q * 8);
        o4p[0] = make_float4(a0, a1, a2, a3);
        o4p[1] = make_float4(a4, a5, a6, a7);
    }
}

// ---------------------------------------------------------------------------
// Gather for ITEM rows (neighbor = user row; beta comes from the neighbor).
// ---------------------------------------------------------------------------
__global__ void gatherI_kernel(const unsigned short* __restrict__ xh,
                               const float4* __restrict__ scal,
                               const int* __restrict__ cnt,
                               const unsigned int* __restrict__ ibkt,
                               float* __restrict__ out) {
    int gid  = blockIdx.x * blockDim.x + threadIdx.x;
    int ri   = gid >> 6;                 // item index
    int lane = gid & 63;
    if (ri >= N_ITEMS) return;
    int r = N_USERS + ri;                // row index

    int g = lane >> 3;
    int q = lane & 7;

    float4 sc = scal[r];
    uint4 hs = *(const uint4*)(xh + (size_t)r * D + q * 8);
    float xs0 = BF_LO(hs.x), xs1 = BF_HI(hs.x);
    float xs2 = BF_LO(hs.y), xs3 = BF_HI(hs.y);
    float xs4 = BF_LO(hs.z), xs5 = BF_HI(hs.z);
    float xs6 = BF_LO(hs.w), xs7 = BF_HI(hs.w);

    int deg = cnt[r];
    if (deg > IPAD) deg = IPAD;
    int iters = (deg + 7) >> 3;

    float a0=0.f,a1=0.f,a2=0.f,a3=0.f,a4=0.f,a5=0.f,a6=0.f,a7=0.f;

    for (int it = 0; it < iters; ++it) {
        int idx = it * 8 + g;
        bool valid = (idx < deg);
        int nb = (int)ibkt[(size_t)ri * IPAD + (valid ? idx : 0)];

        float4 so = scal[nb];
        uint4 ho = *(const uint4*)(xh + (size_t)nb * D + q * 8);
        float o0 = BF_LO(ho.x), o1 = BF_HI(ho.x);
        float o2 = BF_LO(ho.y), o3 = BF_HI(ho.y);
        float o4 = BF_LO(ho.z), o5 = BF_HI(ho.z);
        float o6 = BF_LO(ho.w), o7 = BF_HI(ho.w);

        float p = xs0*o0 + xs1*o1 + xs2*o2 + xs3*o3
                + xs4*o4 + xs5*o5 + xs6*o6 + xs7*o7;
        p += __shfl_xor(p, 1);
        p += __shfl_xor(p, 2);
        p += __shfl_xor(p, 4);

        float sv  = p * sc.x * so.x - so.z;          // neighbor (user) beta
        float sig = 1.0f / (1.0f + __expf(-sv));
        float w   = 4.0f * sig * (1.0f - sig) * sc.y * so.y;
        w = valid ? w : 0.0f;

        a0 = fmaf(w, o0, a0); a1 = fmaf(w, o1, a1);
        a2 = fmaf(w, o2, a2); a3 = fmaf(w, o3, a3);
        a4 = fmaf(w, o4, a4); a5 = fmaf(w, o5, a5);
        a6 = fmaf(w, o6, a6); a7 = fmaf(w, o7, a7);
    }

    #pragma unroll
    for (int m = 8; m <= 32; m <<= 1) {
        a0 += __shfl_xor(a0, m); a1 += __shfl_xor(a1, m);
        a2 += __shfl_xor(a2, m); a3 += __shfl_xor(a3, m);
        a4 += __shfl_xor(a4, m); a5 += __shfl_xor(a5, m);
        a6 += __shfl_xor(a6, m); a7 += __shfl_xor(a7, m);
    }

    if (g == 0) {
        float4* o4p = (float4*)(out + (size_t)r * D + q * 8);
        o4p[0] = make_float4(a0, a1, a2, a3);
        o4p[1] = make_float4(a4, a5, a6, a7);
    }
}

// ---------------------------------------------------------------------------
// Overflow fixer: recompute w for spilled edges (fp32), atomic-add into the
// overflowed side's row. Normally zero work.
// ---------------------------------------------------------------------------
__global__ void ovf_kernel(const float* __restrict__ x,
                           const float4* __restrict__ scal,
                           const int* __restrict__ u,
                           const int* __restrict__ i,
                           const int* __restrict__ ovfc,
                           const int* __restrict__ ovf,
                           float* __restrict__ out) {
    int n = *ovfc;
    if (n > OVF_CAP) n = OVF_CAP;
    int gid  = blockIdx.x * blockDim.x + threadIdx.x;
    int wave = gid >> 6;
    int lane = gid & 63;
    int nw   = (gridDim.x * blockDim.x) >> 6;

    for (int k = wave; k < n; k += nw) {
        int pk = ovf[k];
        int e = pk >> 1, side = pk & 1;
        int uu = u[e];
        int ir = N_USERS + i[e];
        float xu = x[uu * D + lane];
        float xi = x[ir * D + lane];
        float p = xu * xi;
        #pragma unroll
        for (int m = 32; m >= 1; m >>= 1) p += __shfl_xor(p, m);
        float4 su = scal[uu];
        float4 si = scal[ir];
        float sv  = p * su.x * si.x - su.z;
        float sig = 1.0f / (1.0f + __expf(-sv));
        float w   = 4.0f * sig * (1.0f - sig) * su.y * si.y;
        if (side == 0) atomicAdd(&out[(size_t)uu * D + lane], w * xi);
        else           atomicAdd(&out[(size_t)ir * D + lane], w * xu);
    }
}

// ---------------------------------------------------------------------------
// Tier C (round-3 proven linked-list path)
// ---------------------------------------------------------------------------
__global__ void scal_kernel(const float* __restrict__ x,
                            const float* __restrict__ beta,
                            const float* __restrict__ du,
                            const float* __restrict__ di,
                            float4* __restrict__ scal) {
    int gid  = blockIdx.x * blockDim.x + threadIdx.x;
    int r    = gid >> 6;
    int lane = gid & 63;
    if (r >= NR) return;
    float v  = x[r * D + lane];
    float ss = v * v;
    #pragma unroll
    for (int m = 32; m >= 1; m >>= 1) ss += __shfl_xor(ss, m);
    if (lane == 0) {
        float invn = 1.0f / fmaxf(sqrtf(ss), EPS);
        float deg  = (r < N_USERS) ? du[r] : di[r - N_USERS];
        float b    = (r < N_USERS) ? beta[r] : 0.0f;
        scal[r] = make_float4(invn, rsqrtf(deg), b, 0.0f);
    }
}

__global__ void link_kernel(const int* __restrict__ u,
                            const int* __restrict__ i,
                            int* __restrict__ head,
                            int* __restrict__ next_u,
                            int* __restrict__ next_i) {
    int e = blockIdx.x * blockDim.x + threadIdx.x;
    if (e >= N_EDGES) return;
    int uu = u[e];
    int ii = N_USERS + i[e];
    next_u[e] = atomicExch(&head[uu], e);
    next_i[e] = atomicExch(&head[ii], e);
}

__global__ void gather_kernel(const float4* __restrict__ x4,
                              const float4* __restrict__ scal,
                              const int* __restrict__ head,
                              const int* __restrict__ next_u,
                              const int* __restrict__ next_i,
                              const int* __restrict__ u,
                              const int* __restrict__ i,
                              float4* __restrict__ out4) {
    int gid  = blockIdx.x * blockDim.x + threadIdx.x;
    int r    = gid >> 6;
    int lane = gid & 63;
    if (r >= NR) return;
    int g = lane >> 4;
    int q = lane & 15;
    bool isu = (r < N_USERS);
    const int* __restrict__ nxt = isu ? next_u : next_i;
    const int* __restrict__ oid = isu ? i : u;
    int obase = isu ? N_USERS : 0;
    float4 sc = scal[r];
    float4 xs = x4[r * 16 + q];
    float4 acc = make_float4(0.f, 0.f, 0.f, 0.f);
    int e  = head[r];
    int c0 = e; { int t = nxt[(c0 >= 0) ? c0 : 0]; e = (c0 >= 0) ? t : -1; }
    int c1 = e; { int t = nxt[(c1 >= 0) ? c1 : 0]; e = (c1 >= 0) ? t : -1; }
    int c2 = e; { int t = nxt[(c2 >= 0) ? c2 : 0]; e = (c2 >= 0) ? t : -1; }
    int c3 = e; { int t = nxt[(c3 >= 0) ? c3 : 0]; e = (c3 >= 0) ? t : -1; }
    while (c0 >= 0) {
        int n0 = e; { int t = nxt[(n0 >= 0) ? n0 : 0]; e = (n0 >= 0) ? t : -1; }
        int n1 = e; { int t = nxt[(n1 >= 0) ? n1 : 0]; e = (n1 >= 0) ? t : -1; }
        int n2 = e; { int t = nxt[(n2 >= 0) ? n2 : 0]; e = (n2 >= 0) ? t : -1; }
        int n3 = e; { int t = nxt[(n3 >= 0) ? n3 : 0]; e = (n3 >= 0) ? t : -1; }
        int eg = (g == 0) ? c0 : (g == 1) ? c1 : (g == 2) ? c2 : c3;
        bool valid = (eg >= 0);
        int  es = valid ? eg : c0;
        int  nb = obase + oid[es];
        float4 so = scal[nb];
        float4 xo = x4[nb * 16 + q];
        float p = xs.x * xo.x + xs.y * xo.y + xs.z * xo.z + xs.w * xo.w;
        p += __shfl_xor(p, 1);
        p += __shfl_xor(p, 2);
        p += __shfl_xor(p, 4);
        p += __shfl_xor(p, 8);
        float b   = isu ? sc.z : so.z;
        float sv  = p * sc.x * so.x - b;
        float sig = 1.0f / (1.0f + __expf(-sv));
        float w   = 4.0f * sig * (1.0f - sig) * sc.y * so.y;
        w = valid ? w : 0.0f;
        acc.x = fmaf(w, xo.x, acc.x);
        acc.y = fmaf(w, xo.y, acc.y);
        acc.z = fmaf(w, xo.z, acc.z);
        acc.w = fmaf(w, xo.w, acc.w);
        c0 = n0; c1 = n1; c2 = n2; c3 = n3;
    }
    acc.x += __shfl_xor(acc.x, 16); acc.y += __shfl_xor(acc.y, 16);
    acc.z += __shfl_xor(acc.z, 16); acc.w += __shfl_xor(acc.w, 16);
    acc.x += __shfl_xor(acc.x, 32); acc.y += __shfl_xor(acc.y, 32);
    acc.z += __shfl_xor(acc.z, 32); acc.w += __shfl_xor(acc.w, 32);
    if (g == 0) out4[r * 16 + q] = acc;
}

// ---------------------------------------------------------------------------
// Tier D (round-1 atomic fallback)
// ---------------------------------------------------------------------------
__global__ void norm_kernel(const float* __restrict__ x,
                            float* __restrict__ invn,
                            int nrows) {
    int gid  = blockIdx.x * blockDim.x + threadIdx.x;
    int wave = gid >> 6;
    int lane = gid & 63;
    if (wave >= nrows) return;
    float v  = x[wave * D + lane];
    float ss = v * v;
    #pragma unroll
    for (int m = 32; m >= 1; m >>= 1) ss += __shfl_xor(ss, m);
    if (lane == 0) invn[wave] = 1.0f / fmaxf(sqrtf(ss), EPS);
}

__global__ void edge_kernel(const float* __restrict__ x,
                            const float* __restrict__ beta,
                            const float* __restrict__ du,
                            const float* __restrict__ di,
                            const int*   __restrict__ u,
                            const int*   __restrict__ i,
                            const float* __restrict__ invn,
                            float* __restrict__ out) {
    int gid  = blockIdx.x * blockDim.x + threadIdx.x;
    int wave = gid >> 6;
    int lane = gid & 63;
    if (wave >= N_EDGES) return;
    int uu = u[wave];
    int ii = i[wave];
    const float xu = x[uu * D + lane];
    const float xi = x[(N_USERS + ii) * D + lane];
    float p = xu * xi;
    #pragma unroll
    for (int m = 32; m >= 1; m >>= 1) p += __shfl_xor(p, m);
    float s   = p * invn[uu] * invn[N_USERS + ii] - beta[uu];
    float sig = 1.0f / (1.0f + __expf(-s));
    float w   = 4.0f * sig * (1.0f - sig) * rsqrtf(du[uu]) * rsqrtf(di[ii]);
    atomicAdd(&out[uu * D + lane],             w * xi);
    atomicAdd(&out[(N_USERS + ii) * D + lane], w * xu);
}

// ---------------------------------------------------------------------------
extern "C" void kernel_launch(void* const* d_in, const int* in_sizes, int n_in,
                              void* d_out, int out_size, void* d_ws, size_t ws_size,
                              hipStream_t stream) {
    const float* x    = (const float*)d_in[0];
    const float* beta = (const float*)d_in[1];
    const float* du   = (const float*)d_in[2];
    const float* di   = (const float*)d_in[3];
    const int*   u    = (const int*)d_in[4];
    const int*   i    = (const int*)d_in[5];
    float* out = (float*)d_out;
    char*  ws  = (char*)d_ws;

    if (ws_size >= (size_t)WS_A3) {
        float4*         scal = (float4*)(ws + SCAL_OFF);
        unsigned short* xh   = (unsigned short*)(ws + XH_OFF);
        int*            cnt  = (int*)(ws + CNT_OFF);
        unsigned short* ubkt = (unsigned short*)(ws + UBKT_OFF);
        unsigned int*   ibkt = (unsigned int*)(ws + IBKT_OFF);
        int*            ovfc = (int*)(ws + OVFC_OFF);
        int*            ovf  = (int*)(ws + OVF_OFF);

        prep_kernel<<<(NR + 3) / 4, 256, 0, stream>>>(x, beta, du, di, scal, xh);
        hipMemsetAsync(cnt, 0, (size_t)NR * sizeof(int), stream);
        hipMemsetAsync(ovfc, 0, sizeof(int), stream);
        fillx_kernel<<<NPART * FILL_BPP, 256, 0, stream>>>(u, i, cnt, ubkt, ibkt, ovfc, ovf);
        gatherU_kernel<<<(N_USERS + 3) / 4, 256, 0, stream>>>(xh, scal, cnt, ubkt, out);
        gatherI_kernel<<<(N_ITEMS + 3) / 4, 256, 0, stream>>>(xh, scal, cnt, ibkt, out);
        ovf_kernel<<<64, 256, 0, stream>>>(x, scal, u, i, ovfc, ovf, out);
    } else if (ws_size >= (size_t)WS_C) {
        float4* scal   = (float4*)(ws + C_SCAL);
        int*    head   = (int*)(ws + C_HEAD);
        int*    next_u = (int*)(ws + C_NXTU);
        int*    next_i = (int*)(ws + C_NXTI);

        scal_kernel<<<(NR + 3) / 4, 256, 0, stream>>>(x, beta, du, di, scal);
        hipMemsetAsync(head, 0xFF, (size_t)NR * sizeof(int), stream);
        link_kernel<<<(N_EDGES + 255) / 256, 256, 0, stream>>>(u, i, head, next_u, next_i);
        gather_kernel<<<(NR + 3) / 4, 256, 0, stream>>>((const float4*)x, scal, head,
                                                        next_u, next_i, u, i, (float4*)out);
    } else {
        float* invn = (float*)ws;
        hipMemsetAsync(d_out, 0, (size_t)out_size * sizeof(float), stream);
        norm_kernel<<<(NR + 3) / 4, 256, 0, stream>>>(x, invn, NR);
        edge_kernel<<<(N_EDGES + 3) / 4, 256, 0, stream>>>(x, beta, du, di, u, i, invn, out);
    }
}